// Round 11
// baseline (450.860 us; speedup 1.0000x reference)
//
#include <hip/hip_runtime.h>
#include <hip/hip_bf16.h>
#include <math.h>

#define HID 128
#define NHEAD 4
#define CH 32
#define NLAYER 3
#define EDIM 3
#define EPSLN 1e-5f
#define SLOPE 0.2f
#define RSLOTS 1024   // LN-reduction slots (pairs) per layer
#define PAD_W -1e30f  // additive sentinel: exp2(part + PAD_W) == 0
#define LOG2E 1.4426950408889634f

typedef __bf16 bf16x8 __attribute__((ext_vector_type(8)));
typedef float f32x4 __attribute__((ext_vector_type(4)));
typedef float f32x2 __attribute__((ext_vector_type(2)));

__device__ __forceinline__ float bflo(unsigned d) { return __uint_as_float(d << 16); }
__device__ __forceinline__ float bfhi(unsigned d) { return __uint_as_float(d & 0xffff0000u); }

// sum via row-DPP adds (no LDS pipe)
#define DPP_ADD(x, ctrl) \
    (x + __int_as_float(__builtin_amdgcn_update_dpp(0, __float_as_int(x), ctrl, 0xf, 0xf, true)))

// ---------------------------------------------------------------- degree count
__global__ void k_count(const int* __restrict__ dst, int* __restrict__ deg, int E) {
    int i = blockIdx.x * blockDim.x + threadIdx.x;
    if (i < E) atomicAdd(&deg[dst[i]], 1);
}

// ---------------------------------------------------------------- single-block scan
// Scans per-group totals where group value = sum_{j<4} pad4(deg[4g+j]).
__global__ __launch_bounds__(1024) void k_scan(const int* __restrict__ deg,
                                               int* __restrict__ outs,
                                               int N, int G) {
    __shared__ int sw[16];
    __shared__ int scarry;
    int tid = threadIdx.x, lane = tid & 63, wid = tid >> 6;
    if (tid == 0) scarry = 0;
    __syncthreads();
    for (int base = 0; base < G; base += 1024) {
        int i = base + tid;
        int v = 0;
        if (i < G) {
            int n0 = 4 * i;
            if (n0 + 3 < N) {
                int4 d4 = *(const int4*)&deg[n0];
                v = ((d4.x + 3) & ~3) + ((d4.y + 3) & ~3) +
                    ((d4.z + 3) & ~3) + ((d4.w + 3) & ~3);
            } else {
#pragma unroll
                for (int j = 0; j < 4; j++) {
                    int n = n0 + j;
                    if (n < N) v += (deg[n] + 3) & ~3;
                }
            }
        }
        int x = v;
#pragma unroll
        for (int o = 1; o < 64; o <<= 1) { int y = __shfl_up(x, o, 64); if (lane >= o) x += y; }
        if (lane == 63) sw[wid] = x;
        __syncthreads();
        int carry = scarry;
        if (tid < 16) {
            int s = sw[tid];
#pragma unroll
            for (int o = 1; o < 16; o <<= 1) { int y = __shfl_up(s, o, 64); if (tid >= o) s += y; }
            sw[tid] = s;
        }
        __syncthreads();
        int wofs = (wid == 0) ? 0 : sw[wid - 1];
        int incl = carry + wofs + x;
        if (i < G) outs[i] = incl - v;
        __syncthreads();
        if (tid == 0) scarry = carry + sw[15];
        __syncthreads();
    }
    if (tid == 0) outs[G] = scarry;
}

// ---------------------------------------------------------------- per-node base + pad init
// slotbase[i]=cursor[i]= groupstart[i>>2] + earlier nodes' pad4(deg) in group.
// Initializes ONLY the pad slots (deg..pad4-1): {src=-1, e=0}.
__global__ void k_nodepad(const int* __restrict__ deg, const int* __restrict__ groupstart,
                          int* __restrict__ slotbase, int* __restrict__ cursor,
                          int4* __restrict__ slots, int N) {
    int i = blockIdx.x * blockDim.x + threadIdx.x;
    if (i >= N) return;
    int g = i >> 2;
    int base = groupstart[g];
    int i0 = g * 4;
#pragma unroll
    for (int j = 0; j < 3; j++)
        if (i0 + j < i) base += (deg[i0 + j] + 3) & ~3;
    slotbase[i] = base;
    cursor[i] = base;
    int d = deg[i];
    int pd = (d + 3) & ~3;
    for (int j = d; j < pd; j++) slots[base + j] = make_int4(-1, 0, 0, 0);
}

// one 16B scattered store per edge: {src, e0, e1, e2}
__global__ void k_fill2(const int* __restrict__ src, const int* __restrict__ dst,
                        const float* __restrict__ eattr, int* __restrict__ cursor,
                        int4* __restrict__ slots, int E) {
    int i = blockIdx.x * blockDim.x + threadIdx.x;
    if (i < E) {
        int n = dst[i];
        int slot = atomicAdd(&cursor[n], 1);
        slots[slot] = make_int4(src[i], __float_as_int(eattr[3 * i]),
                                __float_as_int(eattr[3 * i + 1]),
                                __float_as_int(eattr[3 * i + 2]));
    }
}

// ---------------------------------------------------------------- weight prep
// bf16 + MFMA B-fragment swizzle: wz[((s*8+n)*64+q)*8+j] = W[(s*32+(q>>4)*8+j)*128 + n*16+(q&15)]
__global__ __launch_bounds__(256) void k_wprep(const float* __restrict__ Wl,
                                               const float* __restrict__ Wr,
                                               const float* __restrict__ Wout,
                                               __hip_bfloat16* __restrict__ wz) {
    int b = blockIdx.x;  // 0..6: l0Wl,l0Wr,l1Wl,l1Wr,l2Wl,l2Wr,Wout
    const float* src = (b < 6) ? ((b & 1) ? Wr + (size_t)(b >> 1) * 16384
                                          : Wl + (size_t)(b >> 1) * 16384)
                               : Wout;
    for (int t = threadIdx.x; t < 16384; t += 256) {
        int j = t & 7, q = (t >> 3) & 63, n = (t >> 9) & 7, s = t >> 12;
        int k = s * 32 + (q >> 4) * 8 + j;
        int c = n * 16 + (q & 15);
        wz[(size_t)b * 16384 + t] = __float2bfloat16(src[k * 128 + c]);
    }
}

// ---------------------------------------------------------------- MFMA GEMM (merged Wl/Wr, fused LN+gelu)
// AIN==0: A rows from fp32 X, cast bf16 in-register. AIN==1: A rows from packed-bf16
// tmpp with LN+gelu applied in-register (exact old k_ln_gelu op sequence).
// NW==2: both weight mats staged in LDS; A fragments computed ONCE, two MFMA phases
// (Wz0 -> Y0, Wz1 -> Y1). NW==1: single phase (final layer).
template <int AIN, int NW, bool BF16OUT>
__global__ __launch_bounds__(256) void k_gemm_mfma(const void* __restrict__ Xv,
                                                   const __hip_bfloat16* __restrict__ Wz0,
                                                   const __hip_bfloat16* __restrict__ Wz1,
                                                   void* __restrict__ Y0v,
                                                   void* __restrict__ Y1v,
                                                   const float* __restrict__ bias,
                                                   const float* __restrict__ lnw,
                                                   const float* __restrict__ lnb,
                                                   const float* __restrict__ red,
                                                   float M, int N) {
    __shared__ __hip_bfloat16 sW[NW == 2 ? 32768 : 16384];  // 64 KB / 32 KB
    __shared__ float swb[256];            // lnw[0:128] | lnb[0:128]
    __shared__ float ls[8];
    int tid = threadIdx.x;
    {
        const float4* s4 = (const float4*)Wz0;
        float4* d4 = (float4*)sW;
#pragma unroll
        for (int i = 0; i < 8; i++) d4[tid + 256 * i] = s4[tid + 256 * i];
        if (NW == 2) {
            const float4* s41 = (const float4*)Wz1;
            float4* d41 = (float4*)(sW + 16384);
#pragma unroll
            for (int i = 0; i < 8; i++) d41[tid + 256 * i] = s41[tid + 256 * i];
        }
    }
    if (AIN == 1) {
        if (tid < 128) swb[tid] = lnw[tid];
        else swb[tid] = lnb[tid - 128];
        float s = 0.f, q = 0.f;
        const float2* r2 = (const float2*)red;
        for (int i = tid; i < RSLOTS; i += 256) { float2 rv = r2[i]; s += rv.x; q += rv.y; }
#pragma unroll
        for (int o = 32; o >= 1; o >>= 1) { s += __shfl_xor(s, o); q += __shfl_xor(q, o); }
        if ((tid & 63) == 0) { ls[(tid >> 6) * 2] = s; ls[(tid >> 6) * 2 + 1] = q; }
    }
    __syncthreads();
    float mean = 0.f, inv = 0.f;
    if (AIN == 1) {
        float S = ls[0] + ls[2] + ls[4] + ls[6];
        float Q = ls[1] + ls[3] + ls[5] + ls[7];
        mean = S / M;
        inv = rsqrtf(Q / M - mean * mean + EPSLN);
    }

    int wv = tid >> 6, lane = tid & 63;
    int quad = lane >> 4, l16 = lane & 15;
    int mbase = blockIdx.x * 128 + wv * 32;

    // ---- activated A fragments, computed ONCE (32 VGPRs)
    bf16x8 afr[4][2];
#pragma unroll
    for (int s = 0; s < 4; s++) {
#pragma unroll
        for (int mt = 0; mt < 2; mt++) {
            int row = mbase + mt * 16 + l16;
            row = (row < N) ? row : (N - 1);
            int chb = s * 32 + quad * 8;
            if (AIN == 0) {
                const float* X = (const float*)Xv;
                float4 u0 = *(const float4*)&X[(size_t)row * HID + chb];
                float4 u1 = *(const float4*)&X[(size_t)row * HID + chb + 4];
                __hip_bfloat16 h[8] = {__float2bfloat16(u0.x), __float2bfloat16(u0.y),
                                       __float2bfloat16(u0.z), __float2bfloat16(u0.w),
                                       __float2bfloat16(u1.x), __float2bfloat16(u1.y),
                                       __float2bfloat16(u1.z), __float2bfloat16(u1.w)};
                afr[s][mt] = *(bf16x8*)h;
            } else {
                const unsigned* T = (const unsigned*)Xv;
                uint4 v = *(const uint4*)&T[(size_t)row * (HID / 2) + (chb >> 1)];
                float4 w0 = *(const float4*)&swb[chb], w1 = *(const float4*)&swb[chb + 4];
                float4 b0 = *(const float4*)&swb[128 + chb], b1 = *(const float4*)&swb[128 + chb + 4];
                float r[8] = {bflo(v.x), bfhi(v.x), bflo(v.y), bfhi(v.y),
                              bflo(v.z), bfhi(v.z), bflo(v.w), bfhi(v.w)};
                float wr[8] = {w0.x, w0.y, w0.z, w0.w, w1.x, w1.y, w1.z, w1.w};
                float br[8] = {b0.x, b0.y, b0.z, b0.w, b1.x, b1.y, b1.z, b1.w};
                __hip_bfloat16 h[8];
#pragma unroll
                for (int j = 0; j < 8; j++) {
                    float t = fmaf((r[j] - mean) * inv, wr[j], br[j]);
                    h[j] = __float2bfloat16(0.5f * t * (1.f + erff(t * 0.70710678118654752f)));
                }
                afr[s][mt] = *(bf16x8*)h;
            }
        }
    }

    float bv[8];
#pragma unroll
    for (int n = 0; n < 8; n++) bv[n] = bias ? bias[n * 16 + l16] : 0.f;

    // ---- MFMA phases (acc registers reused across phases)
#pragma unroll
    for (int ym = 0; ym < NW; ym++) {
        const __hip_bfloat16* sWp = sW + ym * 16384;
        void* Yv = ym ? Y1v : Y0v;
        f32x4 acc[2][8];
#pragma unroll
        for (int mt = 0; mt < 2; mt++)
#pragma unroll
            for (int n = 0; n < 8; n++) acc[mt][n] = (f32x4){0.f, 0.f, 0.f, 0.f};
#pragma unroll
        for (int s = 0; s < 4; s++) {
#pragma unroll
            for (int n = 0; n < 8; n++) {
                bf16x8 b = *(const bf16x8*)&sWp[((s * 8 + n) * 64 + lane) * 8];
                acc[0][n] = __builtin_amdgcn_mfma_f32_16x16x32_bf16(afr[s][0], b, acc[0][n], 0, 0, 0);
                acc[1][n] = __builtin_amdgcn_mfma_f32_16x16x32_bf16(afr[s][1], b, acc[1][n], 0, 0, 0);
            }
        }
#pragma unroll
        for (int mt = 0; mt < 2; mt++)
#pragma unroll
            for (int reg = 0; reg < 4; reg++) {
                int row = mbase + mt * 16 + quad * 4 + reg;
                if (row < N) {
                    if (BF16OUT) {
                        __hip_bfloat16* yp = (__hip_bfloat16*)Yv + (size_t)row * HID + l16;
#pragma unroll
                        for (int n = 0; n < 8; n++) yp[n * 16] = __float2bfloat16(acc[mt][n][reg]);
                    } else {
                        float* yp = (float*)Yv + (size_t)row * HID + l16;
#pragma unroll
                        for (int n = 0; n < 8; n++) yp[n * 16] = acc[mt][n][reg] + bv[n];
                    }
                }
            }
    }
}

// ---------------------------------------------------------------- GATv2 aggregate (per-node)
// One wave per node (R5 structure): lane owns 2 channels of EVERY edge; 4 edges/step.
// Slot record: int4 {src(-1=pad), e0, e1, e2}; records wave-uniform (scalar loads).
// PAIR-UNROLLED: 8 records + 8 independent 4B gathers issued per iteration, then
// 8 edge-computes; wave-uniform tail step.
__global__ __launch_bounds__(256) void k_aggregate(const __hip_bfloat16* __restrict__ xlb,
                                                   const __hip_bfloat16* __restrict__ xrb,
                                                   const int4* __restrict__ slots,
                                                   const int* __restrict__ deg,
                                                   const int* __restrict__ slotbase,
                                                   const float* __restrict__ We,
                                                   const float* __restrict__ att,
                                                   unsigned* __restrict__ tmpp,
                                                   float* __restrict__ red, int N) {
    int wid = threadIdx.x >> 6;
    int lane = threadIdx.x & 63;
    int node = blockIdx.x * 4 + wid;
    if (node >= N) return;
    int c0 = lane * 2;
    int head = lane >> 4;

    f32x2 we0, we1, we2;
    { float2 t = *(const float2*)&We[c0];            we0 = (f32x2){t.x, t.y}; }
    { float2 t = *(const float2*)&We[HID + c0];      we1 = (f32x2){t.x, t.y}; }
    { float2 t = *(const float2*)&We[2 * HID + c0];  we2 = (f32x2){t.x, t.y}; }
    float at0 = att[head * CH + (c0 & 31)] * LOG2E;        // fold log2e: exp2(m.at') == exp(m.at)
    float at1 = att[head * CH + (c0 & 31) + 1] * LOG2E;

    int base = __builtin_amdgcn_readfirstlane(slotbase[node]);
    int steps = __builtin_amdgcn_readfirstlane((deg[node] + 3) >> 2);

    unsigned dxr = *(const unsigned*)&xrb[(size_t)node * HID + c0];
    f32x2 xr2 = (f32x2){bflo(dxr), bfhi(dxr)};

    float l = 0.f;
    f32x2 Av = (f32x2){0.f, 0.f};

    const int4* vp = slots + base;

// 4B gather of this edge's 2 channels (pad -> row 0, in-bounds)
#define GATH2(v, d) { int si = max((v).x, 0); \
    d = *(const unsigned*)&xlb[(size_t)si * HID + c0]; }

// per-edge compute
#define EDGE(v, d) {                                                          \
    float e0 = __int_as_float((v).y);                                         \
    float e1 = __int_as_float((v).z);                                         \
    float e2 = __int_as_float((v).w);                                         \
    float padw = ((v).x < 0) ? PAD_W : 0.f;                                   \
    f32x2 xv = (f32x2){bflo(d), bfhi(d)};                                     \
    f32x2 m = __builtin_elementwise_fma(we2, (f32x2)e2, xv + xr2);            \
    m = __builtin_elementwise_fma(we1, (f32x2)e1, m);                         \
    m = __builtin_elementwise_fma(we0, (f32x2)e0, m);                         \
    m = __builtin_elementwise_max(m, m * SLOPE);                              \
    float part = fmaf(m.x, at0, m.y * at1);                                   \
    part = DPP_ADD(part, 0xB1);   /* quad_perm [1,0,3,2] */                   \
    part = DPP_ADD(part, 0x4E);   /* quad_perm [2,3,0,1] */                   \
    part = DPP_ADD(part, 0x141);  /* row_half_mirror (^7) */                  \
    part = DPP_ADD(part, 0x140);  /* row_mirror (^15) */                      \
    float p = __builtin_amdgcn_exp2f(part + padw);                            \
    l += p;                                                                   \
    Av = __builtin_elementwise_fma((f32x2)p, xv, Av);                         \
}

    int t = 0;
    for (; t + 2 <= steps; t += 2) {
        // 8 wave-uniform record loads (scalar pipe) ...
        int4 v0 = vp[4 * t + 0], v1 = vp[4 * t + 1], v2 = vp[4 * t + 2], v3 = vp[4 * t + 3];
        int4 v4 = vp[4 * t + 4], v5 = vp[4 * t + 5], v6 = vp[4 * t + 6], v7 = vp[4 * t + 7];
        // ... then 8 independent gathers in flight
        unsigned d0, d1, d2, d3, d4, d5, d6, d7;
        GATH2(v0, d0); GATH2(v1, d1); GATH2(v2, d2); GATH2(v3, d3);
        GATH2(v4, d4); GATH2(v5, d5); GATH2(v6, d6); GATH2(v7, d7);
        EDGE(v0, d0); EDGE(v1, d1); EDGE(v2, d2); EDGE(v3, d3);
        EDGE(v4, d4); EDGE(v5, d5); EDGE(v6, d6); EDGE(v7, d7);
    }
    if (t < steps) {  // wave-uniform tail (steps odd)
        int4 v0 = vp[4 * t + 0], v1 = vp[4 * t + 1], v2 = vp[4 * t + 2], v3 = vp[4 * t + 3];
        unsigned d0, d1, d2, d3;
        GATH2(v0, d0); GATH2(v1, d1); GATH2(v2, d2); GATH2(v3, d3);
        EDGE(v0, d0); EDGE(v1, d1); EDGE(v2, d2); EDGE(v3, d3);
    }
#undef GATH2
#undef EDGE

    float inv = 1.f / (l + 1e-16f);
    f32x2 o2 = Av * inv;
    __hip_bfloat16 pk[2] = {__float2bfloat16(o2.x), __float2bfloat16(o2.y)};
    tmpp[(size_t)node * (HID / 2) + lane] = *(unsigned*)pk;

    float ssum = o2.x + o2.y;             // LN stats from pre-rounded fp32
    float ssq = fmaf(o2.x, o2.x, o2.y * o2.y);
#pragma unroll
    for (int o = 32; o >= 1; o >>= 1) { ssum += __shfl_xor(ssum, o); ssq += __shfl_xor(ssq, o); }
    if (lane == 0) {
        int slot = (node & (RSLOTS - 1)) * 2;
        atomicAdd(&red[slot], ssum);
        atomicAdd(&red[slot + 1], ssq);
    }
}

// ---------------------------------------------------------------- launch
extern "C" void kernel_launch(void* const* d_in, const int* in_sizes, int n_in,
                              void* d_out, int out_size, void* d_ws, size_t ws_size,
                              hipStream_t stream) {
    const float* x = (const float*)d_in[0];
    const int* ei = (const int*)d_in[1];
    const float* eattr = (const float*)d_in[2];
    const float* Wl = (const float*)d_in[3];
    const float* Wr = (const float*)d_in[4];
    const float* We = (const float*)d_in[5];
    const float* att = (const float*)d_in[6];
    const float* lnw = (const float*)d_in[7];
    const float* lnb = (const float*)d_in[8];
    const float* Wout = (const float*)d_in[9];
    const float* bout = (const float*)d_in[10];
    float* out = (float*)d_out;

    int N = in_sizes[0] / HID;
    int E = in_sizes[1] / 2;
    int G = (N + 3) / 4;
    int SCAP = E + 8 * N;
    const int* src = ei;
    const int* dst = ei + E;

    char* w = (char*)d_ws;
    __hip_bfloat16* xlb = (__hip_bfloat16*)w;  w += (size_t)N * HID * 2;
    __hip_bfloat16* xrb = (__hip_bfloat16*)w;  w += (size_t)N * HID * 2;
    unsigned* tmpp = (unsigned*)w;             w += (size_t)N * HID * 2;
    __hip_bfloat16* wz = (__hip_bfloat16*)w;   w += (size_t)7 * 16384 * 2;
    int4* slots = (int4*)w;       w += (size_t)SCAP * 16;
    // zero-region: deg, cursor, red (3 layers) contiguous -> ONE memset
    int* deg = (int*)w;           w += (size_t)N * 4;
    int* cursor = (int*)w;        w += (size_t)N * 4;
    float* red = (float*)w;       w += (size_t)NLAYER * RSLOTS * 2 * 4;
    int* slotbase = (int*)w;      w += (size_t)N * 4;
    int* groupstart = (int*)w;    w += (size_t)(G + 1) * 4;

    // ---- build + prep
    hipMemsetAsync(deg, 0, (size_t)(2 * N + NLAYER * RSLOTS * 2) * 4, stream);
    k_count<<<(E + 255) / 256, 256, 0, stream>>>(dst, deg, E);
    k_scan<<<1, 1024, 0, stream>>>(deg, groupstart, N, G);
    k_nodepad<<<(N + 255) / 256, 256, 0, stream>>>(deg, groupstart, slotbase, cursor, slots, N);
    k_fill2<<<(E + 255) / 256, 256, 0, stream>>>(src, dst, eattr, cursor, slots, E);
    k_wprep<<<7, 256, 0, stream>>>(Wl, Wr, Wout, wz);

    int gb = (N + 127) / 128;
    float M = (float)N * (float)HID;
    for (int l = 0; l < NLAYER; l++) {
        float* redl = red + (size_t)l * RSLOTS * 2;
        if (l == 0) {
            k_gemm_mfma<0, 2, true><<<gb, 256, 0, stream>>>(
                x, wz, wz + 16384, xlb, xrb, nullptr, nullptr, nullptr, nullptr, 0.f, N);
        } else {
            k_gemm_mfma<1, 2, true><<<gb, 256, 0, stream>>>(
                tmpp, wz + (size_t)(2 * l) * 16384, wz + (size_t)(2 * l + 1) * 16384,
                xlb, xrb, nullptr,
                lnw + (size_t)(l - 1) * HID, lnb + (size_t)(l - 1) * HID,
                red + (size_t)(l - 1) * RSLOTS * 2, M, N);
        }
        k_aggregate<<<(N + 3) / 4, 256, 0, stream>>>(
            xlb, xrb, slots, deg, slotbase,
            We + (size_t)l * EDIM * HID, att + (size_t)l * NHEAD * CH, tmpp, redl, N);
    }
    k_gemm_mfma<1, 1, false><<<gb, 256, 0, stream>>>(
        tmpp, wz + (size_t)6 * 16384, wz + (size_t)6 * 16384, out, out, bout,
        lnw + (size_t)2 * HID, lnb + (size_t)2 * HID,
        red + (size_t)2 * RSLOTS * 2, M, N);
}

// Round 13
// 398.273 us; speedup vs baseline: 1.1320x; 1.1320x over previous
//
#include <hip/hip_runtime.h>
#include <hip/hip_bf16.h>
#include <math.h>

#define HID 128
#define NHEAD 4
#define CH 32
#define NLAYER 3
#define EDIM 3
#define EPSLN 1e-5f
#define SLOPE 0.2f
#define RSLOTS 1024   // LN-reduction slots (pairs) per layer
#define PAD_W -1e30f  // additive sentinel: exp2(part + PAD_W) == 0
#define LOG2E 1.4426950408889634f

typedef __bf16 bf16x8 __attribute__((ext_vector_type(8)));
typedef float f32x4 __attribute__((ext_vector_type(4)));
typedef float f32x2 __attribute__((ext_vector_type(2)));

__device__ __forceinline__ float bflo(unsigned d) { return __uint_as_float(d << 16); }
__device__ __forceinline__ float bfhi(unsigned d) { return __uint_as_float(d & 0xffff0000u); }

// sum via row-DPP adds (no LDS pipe)
#define DPP_ADD(x, ctrl) \
    (x + __int_as_float(__builtin_amdgcn_update_dpp(0, __float_as_int(x), ctrl, 0xf, 0xf, true)))

// ---------------------------------------------------------------- degree count + edge position
// pos[i] = this edge's arrival index at its destination (reuses the atomic's return value).
__global__ void k_count(const int* __restrict__ dst, int* __restrict__ deg,
                        int* __restrict__ pos, int E) {
    int i = blockIdx.x * blockDim.x + threadIdx.x;
    if (i < E) pos[i] = atomicAdd(&deg[dst[i]], 1);
}

// ---------------------------------------------------------------- single-block scan
// Scans per-group totals where group value = sum_{j<4} pad4(deg[4g+j]).
__global__ __launch_bounds__(1024) void k_scan(const int* __restrict__ deg,
                                               int* __restrict__ outs,
                                               int N, int G) {
    __shared__ int sw[16];
    __shared__ int scarry;
    int tid = threadIdx.x, lane = tid & 63, wid = tid >> 6;
    if (tid == 0) scarry = 0;
    __syncthreads();
    for (int base = 0; base < G; base += 1024) {
        int i = base + tid;
        int v = 0;
        if (i < G) {
            int n0 = 4 * i;
            if (n0 + 3 < N) {
                int4 d4 = *(const int4*)&deg[n0];
                v = ((d4.x + 3) & ~3) + ((d4.y + 3) & ~3) +
                    ((d4.z + 3) & ~3) + ((d4.w + 3) & ~3);
            } else {
#pragma unroll
                for (int j = 0; j < 4; j++) {
                    int n = n0 + j;
                    if (n < N) v += (deg[n] + 3) & ~3;
                }
            }
        }
        int x = v;
#pragma unroll
        for (int o = 1; o < 64; o <<= 1) { int y = __shfl_up(x, o, 64); if (lane >= o) x += y; }
        if (lane == 63) sw[wid] = x;
        __syncthreads();
        int carry = scarry;
        if (tid < 16) {
            int s = sw[tid];
#pragma unroll
            for (int o = 1; o < 16; o <<= 1) { int y = __shfl_up(s, o, 64); if (tid >= o) s += y; }
            sw[tid] = s;
        }
        __syncthreads();
        int wofs = (wid == 0) ? 0 : sw[wid - 1];
        int incl = carry + wofs + x;
        if (i < G) outs[i] = incl - v;
        __syncthreads();
        if (tid == 0) scarry = carry + sw[15];
        __syncthreads();
    }
    if (tid == 0) outs[G] = scarry;
}

// ---------------------------------------------------------------- per-node base + pad init
// slotbase[i] = groupstart[i>>2] + earlier nodes' pad4(deg) in group.
// Initializes ONLY the pad slots (deg..pad4-1): {src=-1, e=0}.
__global__ void k_nodepad(const int* __restrict__ deg, const int* __restrict__ groupstart,
                          int* __restrict__ slotbase, int4* __restrict__ slots, int N) {
    int i = blockIdx.x * blockDim.x + threadIdx.x;
    if (i >= N) return;
    int g = i >> 2;
    int base = groupstart[g];
    int i0 = g * 4;
#pragma unroll
    for (int j = 0; j < 3; j++)
        if (i0 + j < i) base += (deg[i0 + j] + 3) & ~3;
    slotbase[i] = base;
    int d = deg[i];
    int pd = (d + 3) & ~3;
    for (int j = d; j < pd; j++) slots[base + j] = make_int4(-1, 0, 0, 0);
}

// atomic-free: one 16B scattered store per edge: {src, e0, e1, e2}
__global__ void k_fill2(const int* __restrict__ src, const int* __restrict__ dst,
                        const float* __restrict__ eattr, const int* __restrict__ pos,
                        const int* __restrict__ slotbase, int4* __restrict__ slots, int E) {
    int i = blockIdx.x * blockDim.x + threadIdx.x;
    if (i < E) {
        int n = dst[i];
        int slot = slotbase[n] + pos[i];
        slots[slot] = make_int4(src[i], __float_as_int(eattr[3 * i]),
                                __float_as_int(eattr[3 * i + 1]),
                                __float_as_int(eattr[3 * i + 2]));
    }
}

// ---------------------------------------------------------------- weight prep
// bf16 + MFMA B-fragment swizzle: wz[((s*8+n)*64+q)*8+j] = W[(s*32+(q>>4)*8+j)*128 + n*16+(q&15)]
__global__ __launch_bounds__(256) void k_wprep(const float* __restrict__ Wl,
                                               const float* __restrict__ Wr,
                                               const float* __restrict__ Wout,
                                               __hip_bfloat16* __restrict__ wz) {
    int b = blockIdx.x;  // 0..6: l0Wl,l0Wr,l1Wl,l1Wr,l2Wl,l2Wr,Wout
    const float* src = (b < 6) ? ((b & 1) ? Wr + (size_t)(b >> 1) * 16384
                                          : Wl + (size_t)(b >> 1) * 16384)
                               : Wout;
    for (int t = threadIdx.x; t < 16384; t += 256) {
        int j = t & 7, q = (t >> 3) & 63, n = (t >> 9) & 7, s = t >> 12;
        int k = s * 32 + (q >> 4) * 8 + j;
        int c = n * 16 + (q & 15);
        wz[(size_t)b * 16384 + t] = __float2bfloat16(src[k * 128 + c]);
    }
}

__global__ __launch_bounds__(256) void k_cast(const float* __restrict__ in,
                                              __hip_bfloat16* __restrict__ out, int n) {
    int i = (blockIdx.x * 256 + threadIdx.x) * 4;
    if (i < n) {
        float4 v = *(const float4*)&in[i];
        __hip_bfloat16 o[4] = {__float2bfloat16(v.x), __float2bfloat16(v.y),
                               __float2bfloat16(v.z), __float2bfloat16(v.w)};
        *(ushort4*)&out[i] = *(ushort4*)o;
    }
}

// ---------------------------------------------------------------- MFMA GEMM
// Y = Xb(bf16) @ W(bf16 pre-swizzled); out bf16 (layers) or fp32+bias (final).
template <bool BF16OUT>
__global__ __launch_bounds__(256) void k_gemm_mfma(const __hip_bfloat16* __restrict__ Xb,
                                                   const __hip_bfloat16* __restrict__ Wz0,
                                                   const __hip_bfloat16* __restrict__ Wz1,
                                                   void* __restrict__ Y0v,
                                                   void* __restrict__ Y1v,
                                                   const float* __restrict__ bias, int N) {
    __shared__ __hip_bfloat16 sW[16384];  // 32 KB
    const __hip_bfloat16* Wz = blockIdx.y ? Wz1 : Wz0;
    void* Yv = blockIdx.y ? Y1v : Y0v;
    int tid = threadIdx.x;
    {
        const float4* s4 = (const float4*)Wz;
        float4* d4 = (float4*)sW;
#pragma unroll
        for (int i = 0; i < 8; i++) d4[tid + 256 * i] = s4[tid + 256 * i];
    }
    __syncthreads();

    int wv = tid >> 6, lane = tid & 63;
    int quad = lane >> 4, l16 = lane & 15;
    int mbase = blockIdx.x * 128 + wv * 32;

    f32x4 acc[2][8];
#pragma unroll
    for (int mt = 0; mt < 2; mt++)
#pragma unroll
        for (int n = 0; n < 8; n++) acc[mt][n] = (f32x4){0.f, 0.f, 0.f, 0.f};

#pragma unroll
    for (int s = 0; s < 4; s++) {
        bf16x8 a[2];
#pragma unroll
        for (int mt = 0; mt < 2; mt++) {
            int row = mbase + mt * 16 + l16;
            row = (row < N) ? row : (N - 1);
            a[mt] = *(const bf16x8*)&Xb[(size_t)row * HID + s * 32 + quad * 8];
        }
#pragma unroll
        for (int n = 0; n < 8; n++) {
            bf16x8 b = *(const bf16x8*)&sW[((s * 8 + n) * 64 + lane) * 8];
            acc[0][n] = __builtin_amdgcn_mfma_f32_16x16x32_bf16(a[0], b, acc[0][n], 0, 0, 0);
            acc[1][n] = __builtin_amdgcn_mfma_f32_16x16x32_bf16(a[1], b, acc[1][n], 0, 0, 0);
        }
    }

    float bv[8];
#pragma unroll
    for (int n = 0; n < 8; n++) bv[n] = bias ? bias[n * 16 + l16] : 0.f;

#pragma unroll
    for (int mt = 0; mt < 2; mt++)
#pragma unroll
        for (int reg = 0; reg < 4; reg++) {
            int row = mbase + mt * 16 + quad * 4 + reg;
            if (row < N) {
                if (BF16OUT) {
                    __hip_bfloat16* yp = (__hip_bfloat16*)Yv + (size_t)row * HID + l16;
#pragma unroll
                    for (int n = 0; n < 8; n++) yp[n * 16] = __float2bfloat16(acc[mt][n][reg]);
                } else {
                    float* yp = (float*)Yv + (size_t)row * HID + l16;
#pragma unroll
                    for (int n = 0; n < 8; n++) yp[n * 16] = acc[mt][n][reg] + bv[n];
                }
            }
        }
}

// ---------------------------------------------------------------- GATv2 aggregate (per-node)
// One wave per node (R5 structure): lane owns 2 channels of EVERY edge; 4 edges/step.
// Slot record: int4 {src(-1=pad), e0, e1, e2}; records wave-uniform (scalar loads).
// PAIR-UNROLLED: 8 records + 8 independent 4B gathers issued per iteration, then
// 8 edge-computes; wave-uniform tail step.
__global__ __launch_bounds__(256) void k_aggregate(const __hip_bfloat16* __restrict__ xlb,
                                                   const __hip_bfloat16* __restrict__ xrb,
                                                   const int4* __restrict__ slots,
                                                   const int* __restrict__ deg,
                                                   const int* __restrict__ slotbase,
                                                   const float* __restrict__ We,
                                                   const float* __restrict__ att,
                                                   unsigned* __restrict__ tmpp,
                                                   float* __restrict__ red, int N) {
    int wid = threadIdx.x >> 6;
    int lane = threadIdx.x & 63;
    int node = blockIdx.x * 4 + wid;
    if (node >= N) return;
    int c0 = lane * 2;
    int head = lane >> 4;

    f32x2 we0, we1, we2;
    { float2 t = *(const float2*)&We[c0];            we0 = (f32x2){t.x, t.y}; }
    { float2 t = *(const float2*)&We[HID + c0];      we1 = (f32x2){t.x, t.y}; }
    { float2 t = *(const float2*)&We[2 * HID + c0];  we2 = (f32x2){t.x, t.y}; }
    float at0 = att[head * CH + (c0 & 31)] * LOG2E;        // fold log2e: exp2(m.at') == exp(m.at)
    float at1 = att[head * CH + (c0 & 31) + 1] * LOG2E;

    int base = __builtin_amdgcn_readfirstlane(slotbase[node]);
    int steps = __builtin_amdgcn_readfirstlane((deg[node] + 3) >> 2);

    unsigned dxr = *(const unsigned*)&xrb[(size_t)node * HID + c0];
    f32x2 xr2 = (f32x2){bflo(dxr), bfhi(dxr)};

    float l = 0.f;
    f32x2 Av = (f32x2){0.f, 0.f};

    const int4* vp = slots + base;

// 4B gather of this edge's 2 channels (pad -> row 0, in-bounds)
#define GATH2(v, d) { int si = max((v).x, 0); \
    d = *(const unsigned*)&xlb[(size_t)si * HID + c0]; }

// per-edge compute
#define EDGE(v, d) {                                                          \
    float e0 = __int_as_float((v).y);                                         \
    float e1 = __int_as_float((v).z);                                         \
    float e2 = __int_as_float((v).w);                                         \
    float padw = ((v).x < 0) ? PAD_W : 0.f;                                   \
    f32x2 xv = (f32x2){bflo(d), bfhi(d)};                                     \
    f32x2 m = __builtin_elementwise_fma(we2, (f32x2)e2, xv + xr2);            \
    m = __builtin_elementwise_fma(we1, (f32x2)e1, m);                         \
    m = __builtin_elementwise_fma(we0, (f32x2)e0, m);                         \
    m = __builtin_elementwise_max(m, m * SLOPE);                              \
    float part = fmaf(m.x, at0, m.y * at1);                                   \
    part = DPP_ADD(part, 0xB1);   /* quad_perm [1,0,3,2] */                   \
    part = DPP_ADD(part, 0x4E);   /* quad_perm [2,3,0,1] */                   \
    part = DPP_ADD(part, 0x141);  /* row_half_mirror (^7) */                  \
    part = DPP_ADD(part, 0x140);  /* row_mirror (^15) */                      \
    float p = __builtin_amdgcn_exp2f(part + padw);                            \
    l += p;                                                                   \
    Av = __builtin_elementwise_fma((f32x2)p, xv, Av);                         \
}

    int t = 0;
    for (; t + 2 <= steps; t += 2) {
        // 8 wave-uniform record loads (scalar pipe) ...
        int4 v0 = vp[4 * t + 0], v1 = vp[4 * t + 1], v2 = vp[4 * t + 2], v3 = vp[4 * t + 3];
        int4 v4 = vp[4 * t + 4], v5 = vp[4 * t + 5], v6 = vp[4 * t + 6], v7 = vp[4 * t + 7];
        // ... then 8 independent gathers in flight
        unsigned d0, d1, d2, d3, d4, d5, d6, d7;
        GATH2(v0, d0); GATH2(v1, d1); GATH2(v2, d2); GATH2(v3, d3);
        GATH2(v4, d4); GATH2(v5, d5); GATH2(v6, d6); GATH2(v7, d7);
        EDGE(v0, d0); EDGE(v1, d1); EDGE(v2, d2); EDGE(v3, d3);
        EDGE(v4, d4); EDGE(v5, d5); EDGE(v6, d6); EDGE(v7, d7);
    }
    if (t < steps) {  // wave-uniform tail (steps odd)
        int4 v0 = vp[4 * t + 0], v1 = vp[4 * t + 1], v2 = vp[4 * t + 2], v3 = vp[4 * t + 3];
        unsigned d0, d1, d2, d3;
        GATH2(v0, d0); GATH2(v1, d1); GATH2(v2, d2); GATH2(v3, d3);
        EDGE(v0, d0); EDGE(v1, d1); EDGE(v2, d2); EDGE(v3, d3);
    }
#undef GATH2
#undef EDGE

    float inv = 1.f / (l + 1e-16f);
    f32x2 o2 = Av * inv;
    __hip_bfloat16 pk[2] = {__float2bfloat16(o2.x), __float2bfloat16(o2.y)};
    tmpp[(size_t)node * (HID / 2) + lane] = *(unsigned*)pk;

    float ssum = o2.x + o2.y;             // LN stats from pre-rounded fp32
    float ssq = fmaf(o2.x, o2.x, o2.y * o2.y);
#pragma unroll
    for (int o = 32; o >= 1; o >>= 1) { ssum += __shfl_xor(ssum, o); ssq += __shfl_xor(ssq, o); }
    if (lane == 0) {
        int slot = (node & (RSLOTS - 1)) * 2;
        atomicAdd(&red[slot], ssum);
        atomicAdd(&red[slot + 1], ssq);
    }
}

// ---------------------------------------------------------------- LN + gelu (bf16 in/out)
// Each block redundantly reduces the layer's red[] (8 KB, L2-hot) -> no separate finish kernel.
__global__ __launch_bounds__(256) void k_ln_gelu(const uint4* __restrict__ in4,
                                                 const float* __restrict__ w,
                                                 const float* __restrict__ b,
                                                 const float* __restrict__ red,
                                                 float M,
                                                 uint4* __restrict__ out4, int n8) {
    __shared__ float ls[8];
    int tid = threadIdx.x;
    float s = 0.f, q = 0.f;
    const float2* r2 = (const float2*)red;
    for (int i = tid; i < RSLOTS; i += 256) { float2 rv = r2[i]; s += rv.x; q += rv.y; }
#pragma unroll
    for (int o = 32; o >= 1; o >>= 1) { s += __shfl_xor(s, o); q += __shfl_xor(q, o); }
    if ((tid & 63) == 0) { ls[(tid >> 6) * 2] = s; ls[(tid >> 6) * 2 + 1] = q; }
    __syncthreads();
    float S = ls[0] + ls[2] + ls[4] + ls[6];
    float Q = ls[1] + ls[3] + ls[5] + ls[7];
    float mean = S / M;
    float inv = rsqrtf(Q / M - mean * mean + EPSLN);

    int i = blockIdx.x * blockDim.x + tid;
    if (i >= n8) return;
    uint4 v = in4[i];
    int col = (i * 8) & 127;
    float4 w0 = *(const float4*)&w[col], w1 = *(const float4*)&w[col + 4];
    float4 b0 = *(const float4*)&b[col], b1 = *(const float4*)&b[col + 4];
    float r[8] = {bflo(v.x), bfhi(v.x), bflo(v.y), bfhi(v.y),
                  bflo(v.z), bfhi(v.z), bflo(v.w), bfhi(v.w)};
    float wr[8] = {w0.x, w0.y, w0.z, w0.w, w1.x, w1.y, w1.z, w1.w};
    float br[8] = {b0.x, b0.y, b0.z, b0.w, b1.x, b1.y, b1.z, b1.w};
    __hip_bfloat16 o[8];
#pragma unroll
    for (int j = 0; j < 8; j++) {
        float t = fmaf((r[j] - mean) * inv, wr[j], br[j]);
        o[j] = __float2bfloat16(0.5f * t * (1.f + erff(t * 0.70710678118654752f)));
    }
    out4[i] = *(uint4*)o;
}

// ---------------------------------------------------------------- launch
extern "C" void kernel_launch(void* const* d_in, const int* in_sizes, int n_in,
                              void* d_out, int out_size, void* d_ws, size_t ws_size,
                              hipStream_t stream) {
    const float* x = (const float*)d_in[0];
    const int* ei = (const int*)d_in[1];
    const float* eattr = (const float*)d_in[2];
    const float* Wl = (const float*)d_in[3];
    const float* Wr = (const float*)d_in[4];
    const float* We = (const float*)d_in[5];
    const float* att = (const float*)d_in[6];
    const float* lnw = (const float*)d_in[7];
    const float* lnb = (const float*)d_in[8];
    const float* Wout = (const float*)d_in[9];
    const float* bout = (const float*)d_in[10];
    float* out = (float*)d_out;

    int N = in_sizes[0] / HID;
    int E = in_sizes[1] / 2;
    int G = (N + 3) / 4;
    int SCAP = E + 8 * N;
    const int* src = ei;
    const int* dst = ei + E;

    char* w = (char*)d_ws;
    __hip_bfloat16* hb = (__hip_bfloat16*)w;   w += (size_t)N * HID * 2;
    __hip_bfloat16* xlb = (__hip_bfloat16*)w;  w += (size_t)N * HID * 2;
    __hip_bfloat16* xrb = (__hip_bfloat16*)w;  w += (size_t)N * HID * 2;
    unsigned* tmpp = (unsigned*)w;             w += (size_t)N * HID * 2;
    __hip_bfloat16* wz = (__hip_bfloat16*)w;   w += (size_t)7 * 16384 * 2;
    int4* slots = (int4*)w;       w += (size_t)SCAP * 16;
    int* pos = (int*)w;           w += (size_t)E * 4;
    // zero-region: deg, red (3 layers) contiguous -> ONE memset
    int* deg = (int*)w;           w += (size_t)N * 4;
    float* red = (float*)w;       w += (size_t)NLAYER * RSLOTS * 2 * 4;
    int* slotbase = (int*)w;      w += (size_t)N * 4;
    int* groupstart = (int*)w;    w += (size_t)(G + 1) * 4;

    // ---- build + prep
    hipMemsetAsync(deg, 0, (size_t)(N + NLAYER * RSLOTS * 2) * 4, stream);
    k_count<<<(E + 255) / 256, 256, 0, stream>>>(dst, deg, pos, E);
    k_scan<<<1, 1024, 0, stream>>>(deg, groupstart, N, G);
    k_nodepad<<<(N + 255) / 256, 256, 0, stream>>>(deg, groupstart, slotbase, slots, N);
    k_fill2<<<(E + 255) / 256, 256, 0, stream>>>(src, dst, eattr, pos, slotbase, slots, E);
    k_wprep<<<7, 256, 0, stream>>>(Wl, Wr, Wout, wz);
    k_cast<<<(N * HID / 4 + 255) / 256, 256, 0, stream>>>(x, hb, N * HID);

    int gb = (N + 127) / 128;
    float M = (float)N * (float)HID;
    for (int l = 0; l < NLAYER; l++) {
        float* redl = red + (size_t)l * RSLOTS * 2;
        k_gemm_mfma<true><<<dim3(gb, 2), 256, 0, stream>>>(
            hb, wz + (size_t)(2 * l) * 16384, wz + (size_t)(2 * l + 1) * 16384,
            xlb, xrb, nullptr, N);
        k_aggregate<<<(N + 3) / 4, 256, 0, stream>>>(
            xlb, xrb, slots, deg, slotbase,
            We + (size_t)l * EDIM * HID, att + (size_t)l * NHEAD * CH, tmpp, redl, N);
        k_ln_gelu<<<((N * HID / 8) + 255) / 256, 256, 0, stream>>>(
            (const uint4*)tmpp, lnw + (size_t)l * HID, lnb + (size_t)l * HID, redl, M,
            (uint4*)hb, N * HID / 8);
    }
    k_gemm_mfma<false><<<dim3(gb, 1), 256, 0, stream>>>(
        hb, wz + (size_t)6 * 16384, wz + (size_t)6 * 16384, out, out, bout, N);
}

// Round 14
// 386.146 us; speedup vs baseline: 1.1676x; 1.0314x over previous
//
#include <hip/hip_runtime.h>
#include <hip/hip_bf16.h>
#include <math.h>

#define HID 128
#define NHEAD 4
#define CH 32
#define NLAYER 3
#define EDIM 3
#define EPSLN 1e-5f
#define SLOPE 0.2f
#define RSLOTS 1024   // LN-reduction slots (pairs) per layer
#define PAD_W -1e30f  // additive sentinel: exp2(part + PAD_W) == 0
#define LOG2E 1.4426950408889634f

typedef __bf16 bf16x8 __attribute__((ext_vector_type(8)));
typedef float f32x4 __attribute__((ext_vector_type(4)));
typedef float f32x2 __attribute__((ext_vector_type(2)));

__device__ __forceinline__ float bflo(unsigned d) { return __uint_as_float(d << 16); }
__device__ __forceinline__ float bfhi(unsigned d) { return __uint_as_float(d & 0xffff0000u); }

// sum via row-DPP adds (no LDS pipe)
#define DPP_ADD(x, ctrl) \
    (x + __int_as_float(__builtin_amdgcn_update_dpp(0, __float_as_int(x), ctrl, 0xf, 0xf, true)))

// ---------------------------------------------------------------- degree count + edge position
// pos[i] = this edge's arrival index at its destination (reuses the atomic's return value).
__global__ void k_count(const int* __restrict__ dst, int* __restrict__ deg,
                        int* __restrict__ pos, int E) {
    int i = blockIdx.x * blockDim.x + threadIdx.x;
    if (i < E) pos[i] = atomicAdd(&deg[dst[i]], 1);
}

// ---------------------------------------------------------------- hierarchical scan, phase A
// Each block scans 1024 group totals (group value = sum_{j<4} pad4(deg[4g+j])) ONCE:
// writes block-LOCAL exclusive prefix to outs[] and the block total to partial[b].
__global__ __launch_bounds__(1024) void k_scanA(const int* __restrict__ deg,
                                                int* __restrict__ outs,
                                                int* __restrict__ partial,
                                                int N, int G) {
    __shared__ int sw[16];
    int tid = threadIdx.x, lane = tid & 63, wid = tid >> 6;
    int i = blockIdx.x * 1024 + tid;
    int v = 0;
    if (i < G) {
        int n0 = 4 * i;
        if (n0 + 3 < N) {
            int4 d4 = *(const int4*)&deg[n0];
            v = ((d4.x + 3) & ~3) + ((d4.y + 3) & ~3) +
                ((d4.z + 3) & ~3) + ((d4.w + 3) & ~3);
        } else {
#pragma unroll
            for (int j = 0; j < 4; j++) {
                int n = n0 + j;
                if (n < N) v += (deg[n] + 3) & ~3;
            }
        }
    }
    int x = v;
#pragma unroll
    for (int o = 1; o < 64; o <<= 1) { int y = __shfl_up(x, o, 64); if (lane >= o) x += y; }
    if (lane == 63) sw[wid] = x;
    __syncthreads();
    if (tid < 16) {
        int s = sw[tid];
#pragma unroll
        for (int o = 1; o < 16; o <<= 1) { int y = __shfl_up(s, o, 64); if (tid >= o) s += y; }
        sw[tid] = s;
    }
    __syncthreads();
    int wofs = (wid == 0) ? 0 : sw[wid - 1];
    int incl = wofs + x;
    if (i < G) outs[i] = incl - v;
    if (tid == 0) partial[blockIdx.x] = sw[15];
}

// ---------------------------------------------------------------- per-node base + pad init
// slotbase[i] = outs[g] + prefix(partial, g>>10) + earlier nodes' pad4(deg) in group.
// Initializes ONLY the pad slots (deg..pad4-1): {src=-1, e=0}.
__global__ void k_nodepad(const int* __restrict__ deg, const int* __restrict__ outs,
                          const int* __restrict__ partial,
                          int* __restrict__ slotbase, int4* __restrict__ slots, int N) {
    int i = blockIdx.x * blockDim.x + threadIdx.x;
    if (i >= N) return;
    int g = i >> 2;
    int boff = 0;
    int nb = g >> 10;
    for (int b = 0; b < nb; b++) boff += partial[b];   // <=12 L2-hot, wave-uniform
    int base = outs[g] + boff;
    int i0 = g * 4;
#pragma unroll
    for (int j = 0; j < 3; j++)
        if (i0 + j < i) base += (deg[i0 + j] + 3) & ~3;
    slotbase[i] = base;
    int d = deg[i];
    int pd = (d + 3) & ~3;
    for (int j = d; j < pd; j++) slots[base + j] = make_int4(-1, 0, 0, 0);
}

// atomic-free: one 16B scattered store per edge: {src, e0, e1, e2}
__global__ void k_fill2(const int* __restrict__ src, const int* __restrict__ dst,
                        const float* __restrict__ eattr, const int* __restrict__ pos,
                        const int* __restrict__ slotbase, int4* __restrict__ slots, int E) {
    int i = blockIdx.x * blockDim.x + threadIdx.x;
    if (i < E) {
        int n = dst[i];
        int slot = slotbase[n] + pos[i];
        slots[slot] = make_int4(src[i], __float_as_int(eattr[3 * i]),
                                __float_as_int(eattr[3 * i + 1]),
                                __float_as_int(eattr[3 * i + 2]));
    }
}

// ---------------------------------------------------------------- weight prep
// bf16 + MFMA B-fragment swizzle: wz[((s*8+n)*64+q)*8+j] = W[(s*32+(q>>4)*8+j)*128 + n*16+(q&15)]
__global__ __launch_bounds__(256) void k_wprep(const float* __restrict__ Wl,
                                               const float* __restrict__ Wr,
                                               const float* __restrict__ Wout,
                                               __hip_bfloat16* __restrict__ wz) {
    int b = blockIdx.x;  // 0..6: l0Wl,l0Wr,l1Wl,l1Wr,l2Wl,l2Wr,Wout
    const float* src = (b < 6) ? ((b & 1) ? Wr + (size_t)(b >> 1) * 16384
                                          : Wl + (size_t)(b >> 1) * 16384)
                               : Wout;
    for (int t = threadIdx.x; t < 16384; t += 256) {
        int j = t & 7, q = (t >> 3) & 63, n = (t >> 9) & 7, s = t >> 12;
        int k = s * 32 + (q >> 4) * 8 + j;
        int c = n * 16 + (q & 15);
        wz[(size_t)b * 16384 + t] = __float2bfloat16(src[k * 128 + c]);
    }
}

__global__ __launch_bounds__(256) void k_cast(const float* __restrict__ in,
                                              __hip_bfloat16* __restrict__ out, int n) {
    int i = (blockIdx.x * 256 + threadIdx.x) * 4;
    if (i < n) {
        float4 v = *(const float4*)&in[i];
        __hip_bfloat16 o[4] = {__float2bfloat16(v.x), __float2bfloat16(v.y),
                               __float2bfloat16(v.z), __float2bfloat16(v.w)};
        *(ushort4*)&out[i] = *(ushort4*)o;
    }
}

// ---------------------------------------------------------------- MFMA GEMM
// Y = Xb(bf16) @ W(bf16 pre-swizzled); out bf16 (layers) or fp32+bias (final).
template <bool BF16OUT>
__global__ __launch_bounds__(256) void k_gemm_mfma(const __hip_bfloat16* __restrict__ Xb,
                                                   const __hip_bfloat16* __restrict__ Wz0,
                                                   const __hip_bfloat16* __restrict__ Wz1,
                                                   void* __restrict__ Y0v,
                                                   void* __restrict__ Y1v,
                                                   const float* __restrict__ bias, int N) {
    __shared__ __hip_bfloat16 sW[16384];  // 32 KB
    const __hip_bfloat16* Wz = blockIdx.y ? Wz1 : Wz0;
    void* Yv = blockIdx.y ? Y1v : Y0v;
    int tid = threadIdx.x;
    {
        const float4* s4 = (const float4*)Wz;
        float4* d4 = (float4*)sW;
#pragma unroll
        for (int i = 0; i < 8; i++) d4[tid + 256 * i] = s4[tid + 256 * i];
    }
    __syncthreads();

    int wv = tid >> 6, lane = tid & 63;
    int quad = lane >> 4, l16 = lane & 15;
    int mbase = blockIdx.x * 128 + wv * 32;

    f32x4 acc[2][8];
#pragma unroll
    for (int mt = 0; mt < 2; mt++)
#pragma unroll
        for (int n = 0; n < 8; n++) acc[mt][n] = (f32x4){0.f, 0.f, 0.f, 0.f};

#pragma unroll
    for (int s = 0; s < 4; s++) {
        bf16x8 a[2];
#pragma unroll
        for (int mt = 0; mt < 2; mt++) {
            int row = mbase + mt * 16 + l16;
            row = (row < N) ? row : (N - 1);
            a[mt] = *(const bf16x8*)&Xb[(size_t)row * HID + s * 32 + quad * 8];
        }
#pragma unroll
        for (int n = 0; n < 8; n++) {
            bf16x8 b = *(const bf16x8*)&sW[((s * 8 + n) * 64 + lane) * 8];
            acc[0][n] = __builtin_amdgcn_mfma_f32_16x16x32_bf16(a[0], b, acc[0][n], 0, 0, 0);
            acc[1][n] = __builtin_amdgcn_mfma_f32_16x16x32_bf16(a[1], b, acc[1][n], 0, 0, 0);
        }
    }

    float bv[8];
#pragma unroll
    for (int n = 0; n < 8; n++) bv[n] = bias ? bias[n * 16 + l16] : 0.f;

#pragma unroll
    for (int mt = 0; mt < 2; mt++)
#pragma unroll
        for (int reg = 0; reg < 4; reg++) {
            int row = mbase + mt * 16 + quad * 4 + reg;
            if (row < N) {
                if (BF16OUT) {
                    __hip_bfloat16* yp = (__hip_bfloat16*)Yv + (size_t)row * HID + l16;
#pragma unroll
                    for (int n = 0; n < 8; n++) yp[n * 16] = __float2bfloat16(acc[mt][n][reg]);
                } else {
                    float* yp = (float*)Yv + (size_t)row * HID + l16;
#pragma unroll
                    for (int n = 0; n < 8; n++) yp[n * 16] = acc[mt][n][reg] + bv[n];
                }
            }
        }
}

// ---------------------------------------------------------------- GATv2 aggregate (per-node)
// One wave per node (R5 structure): lane owns 2 channels of EVERY edge; 4 edges/step.
// Slot record: int4 {src(-1=pad), e0, e1, e2}; records wave-uniform (scalar loads).
// PAIR-UNROLLED: 8 records + 8 independent 4B gathers issued per iteration, then
// 8 edge-computes; wave-uniform tail step.
__global__ __launch_bounds__(256) void k_aggregate(const __hip_bfloat16* __restrict__ xlb,
                                                   const __hip_bfloat16* __restrict__ xrb,
                                                   const int4* __restrict__ slots,
                                                   const int* __restrict__ deg,
                                                   const int* __restrict__ slotbase,
                                                   const float* __restrict__ We,
                                                   const float* __restrict__ att,
                                                   unsigned* __restrict__ tmpp,
                                                   float* __restrict__ red, int N) {
    int wid = threadIdx.x >> 6;
    int lane = threadIdx.x & 63;
    int node = blockIdx.x * 4 + wid;
    if (node >= N) return;
    int c0 = lane * 2;
    int head = lane >> 4;

    f32x2 we0, we1, we2;
    { float2 t = *(const float2*)&We[c0];            we0 = (f32x2){t.x, t.y}; }
    { float2 t = *(const float2*)&We[HID + c0];      we1 = (f32x2){t.x, t.y}; }
    { float2 t = *(const float2*)&We[2 * HID + c0];  we2 = (f32x2){t.x, t.y}; }
    float at0 = att[head * CH + (c0 & 31)] * LOG2E;        // fold log2e: exp2(m.at') == exp(m.at)
    float at1 = att[head * CH + (c0 & 31) + 1] * LOG2E;

    int base = __builtin_amdgcn_readfirstlane(slotbase[node]);
    int steps = __builtin_amdgcn_readfirstlane((deg[node] + 3) >> 2);

    unsigned dxr = *(const unsigned*)&xrb[(size_t)node * HID + c0];
    f32x2 xr2 = (f32x2){bflo(dxr), bfhi(dxr)};

    float l = 0.f;
    f32x2 Av = (f32x2){0.f, 0.f};

    const int4* vp = slots + base;

// 4B gather of this edge's 2 channels (pad -> row 0, in-bounds)
#define GATH2(v, d) { int si = max((v).x, 0); \
    d = *(const unsigned*)&xlb[(size_t)si * HID + c0]; }

// per-edge compute
#define EDGE(v, d) {                                                          \
    float e0 = __int_as_float((v).y);                                         \
    float e1 = __int_as_float((v).z);                                         \
    float e2 = __int_as_float((v).w);                                         \
    float padw = ((v).x < 0) ? PAD_W : 0.f;                                   \
    f32x2 xv = (f32x2){bflo(d), bfhi(d)};                                     \
    f32x2 m = __builtin_elementwise_fma(we2, (f32x2)e2, xv + xr2);            \
    m = __builtin_elementwise_fma(we1, (f32x2)e1, m);                         \
    m = __builtin_elementwise_fma(we0, (f32x2)e0, m);                         \
    m = __builtin_elementwise_max(m, m * SLOPE);                              \
    float part = fmaf(m.x, at0, m.y * at1);                                   \
    part = DPP_ADD(part, 0xB1);   /* quad_perm [1,0,3,2] */                   \
    part = DPP_ADD(part, 0x4E);   /* quad_perm [2,3,0,1] */                   \
    part = DPP_ADD(part, 0x141);  /* row_half_mirror (^7) */                  \
    part = DPP_ADD(part, 0x140);  /* row_mirror (^15) */                      \
    float p = __builtin_amdgcn_exp2f(part + padw);                            \
    l += p;                                                                   \
    Av = __builtin_elementwise_fma((f32x2)p, xv, Av);                         \
}

    int t = 0;
    for (; t + 2 <= steps; t += 2) {
        // 8 wave-uniform record loads (scalar pipe) ...
        int4 v0 = vp[4 * t + 0], v1 = vp[4 * t + 1], v2 = vp[4 * t + 2], v3 = vp[4 * t + 3];
        int4 v4 = vp[4 * t + 4], v5 = vp[4 * t + 5], v6 = vp[4 * t + 6], v7 = vp[4 * t + 7];
        // ... then 8 independent gathers in flight
        unsigned d0, d1, d2, d3, d4, d5, d6, d7;
        GATH2(v0, d0); GATH2(v1, d1); GATH2(v2, d2); GATH2(v3, d3);
        GATH2(v4, d4); GATH2(v5, d5); GATH2(v6, d6); GATH2(v7, d7);
        EDGE(v0, d0); EDGE(v1, d1); EDGE(v2, d2); EDGE(v3, d3);
        EDGE(v4, d4); EDGE(v5, d5); EDGE(v6, d6); EDGE(v7, d7);
    }
    if (t < steps) {  // wave-uniform tail (steps odd)
        int4 v0 = vp[4 * t + 0], v1 = vp[4 * t + 1], v2 = vp[4 * t + 2], v3 = vp[4 * t + 3];
        unsigned d0, d1, d2, d3;
        GATH2(v0, d0); GATH2(v1, d1); GATH2(v2, d2); GATH2(v3, d3);
        EDGE(v0, d0); EDGE(v1, d1); EDGE(v2, d2); EDGE(v3, d3);
    }
#undef GATH2
#undef EDGE

    float inv = 1.f / (l + 1e-16f);
    f32x2 o2 = Av * inv;
    __hip_bfloat16 pk[2] = {__float2bfloat16(o2.x), __float2bfloat16(o2.y)};
    tmpp[(size_t)node * (HID / 2) + lane] = *(unsigned*)pk;

    float ssum = o2.x + o2.y;             // LN stats from pre-rounded fp32
    float ssq = fmaf(o2.x, o2.x, o2.y * o2.y);
#pragma unroll
    for (int o = 32; o >= 1; o >>= 1) { ssum += __shfl_xor(ssum, o); ssq += __shfl_xor(ssq, o); }
    if (lane == 0) {
        int slot = (node & (RSLOTS - 1)) * 2;
        atomicAdd(&red[slot], ssum);
        atomicAdd(&red[slot + 1], ssq);
    }
}

// ---------------------------------------------------------------- LN + gelu (bf16 in/out)
// Each block redundantly reduces the layer's red[] (8 KB, L2-hot) -> no separate finish kernel.
__global__ __launch_bounds__(256) void k_ln_gelu(const uint4* __restrict__ in4,
                                                 const float* __restrict__ w,
                                                 const float* __restrict__ b,
                                                 const float* __restrict__ red,
                                                 float M,
                                                 uint4* __restrict__ out4, int n8) {
    __shared__ float ls[8];
    int tid = threadIdx.x;
    float s = 0.f, q = 0.f;
    const float2* r2 = (const float2*)red;
    for (int i = tid; i < RSLOTS; i += 256) { float2 rv = r2[i]; s += rv.x; q += rv.y; }
#pragma unroll
    for (int o = 32; o >= 1; o >>= 1) { s += __shfl_xor(s, o); q += __shfl_xor(q, o); }
    if ((tid & 63) == 0) { ls[(tid >> 6) * 2] = s; ls[(tid >> 6) * 2 + 1] = q; }
    __syncthreads();
    float S = ls[0] + ls[2] + ls[4] + ls[6];
    float Q = ls[1] + ls[3] + ls[5] + ls[7];
    float mean = S / M;
    float inv = rsqrtf(Q / M - mean * mean + EPSLN);

    int i = blockIdx.x * blockDim.x + tid;
    if (i >= n8) return;
    uint4 v = in4[i];
    int col = (i * 8) & 127;
    float4 w0 = *(const float4*)&w[col], w1 = *(const float4*)&w[col + 4];
    float4 b0 = *(const float4*)&b[col], b1 = *(const float4*)&b[col + 4];
    float r[8] = {bflo(v.x), bfhi(v.x), bflo(v.y), bfhi(v.y),
                  bflo(v.z), bfhi(v.z), bflo(v.w), bfhi(v.w)};
    float wr[8] = {w0.x, w0.y, w0.z, w0.w, w1.x, w1.y, w1.z, w1.w};
    float br[8] = {b0.x, b0.y, b0.z, b0.w, b1.x, b1.y, b1.z, b1.w};
    __hip_bfloat16 o[8];
#pragma unroll
    for (int j = 0; j < 8; j++) {
        float t = fmaf((r[j] - mean) * inv, wr[j], br[j]);
        o[j] = __float2bfloat16(0.5f * t * (1.f + erff(t * 0.70710678118654752f)));
    }
    out4[i] = *(uint4*)o;
}

// ---------------------------------------------------------------- launch
extern "C" void kernel_launch(void* const* d_in, const int* in_sizes, int n_in,
                              void* d_out, int out_size, void* d_ws, size_t ws_size,
                              hipStream_t stream) {
    const float* x = (const float*)d_in[0];
    const int* ei = (const int*)d_in[1];
    const float* eattr = (const float*)d_in[2];
    const float* Wl = (const float*)d_in[3];
    const float* Wr = (const float*)d_in[4];
    const float* We = (const float*)d_in[5];
    const float* att = (const float*)d_in[6];
    const float* lnw = (const float*)d_in[7];
    const float* lnb = (const float*)d_in[8];
    const float* Wout = (const float*)d_in[9];
    const float* bout = (const float*)d_in[10];
    float* out = (float*)d_out;

    int N = in_sizes[0] / HID;
    int E = in_sizes[1] / 2;
    int G = (N + 3) / 4;
    int SCAP = E + 8 * N;
    const int* src = ei;
    const int* dst = ei + E;

    char* w = (char*)d_ws;
    __hip_bfloat16* hb = (__hip_bfloat16*)w;   w += (size_t)N * HID * 2;
    __hip_bfloat16* xlb = (__hip_bfloat16*)w;  w += (size_t)N * HID * 2;
    __hip_bfloat16* xrb = (__hip_bfloat16*)w;  w += (size_t)N * HID * 2;
    unsigned* tmpp = (unsigned*)w;             w += (size_t)N * HID * 2;
    __hip_bfloat16* wz = (__hip_bfloat16*)w;   w += (size_t)7 * 16384 * 2;
    int4* slots = (int4*)w;       w += (size_t)SCAP * 16;
    int* pos = (int*)w;           w += (size_t)E * 4;
    // zero-region: deg, red (3 layers) contiguous -> ONE memset
    int* deg = (int*)w;           w += (size_t)N * 4;
    float* red = (float*)w;       w += (size_t)NLAYER * RSLOTS * 2 * 4;
    int* slotbase = (int*)w;      w += (size_t)N * 4;
    int* groupstart = (int*)w;    w += (size_t)(G + 1) * 4;
    int* partial = (int*)w;       w += 32 * 4;

    // ---- build + prep
    hipMemsetAsync(deg, 0, (size_t)(N + NLAYER * RSLOTS * 2) * 4, stream);
    k_count<<<(E + 255) / 256, 256, 0, stream>>>(dst, deg, pos, E);
    k_scanA<<<(G + 1023) / 1024, 1024, 0, stream>>>(deg, groupstart, partial, N, G);
    k_nodepad<<<(N + 255) / 256, 256, 0, stream>>>(deg, groupstart, partial, slotbase, slots, N);
    k_fill2<<<(E + 255) / 256, 256, 0, stream>>>(src, dst, eattr, pos, slotbase, slots, E);
    k_wprep<<<7, 256, 0, stream>>>(Wl, Wr, Wout, wz);
    k_cast<<<(N * HID / 4 + 255) / 256, 256, 0, stream>>>(x, hb, N * HID);

    int gb = (N + 127) / 128;
    float M = (float)N * (float)HID;
    for (int l = 0; l < NLAYER; l++) {
        float* redl = red + (size_t)l * RSLOTS * 2;
        k_gemm_mfma<true><<<dim3(gb, 2), 256, 0, stream>>>(
            hb, wz + (size_t)(2 * l) * 16384, wz + (size_t)(2 * l + 1) * 16384,
            xlb, xrb, nullptr, N);
        k_aggregate<<<(N + 3) / 4, 256, 0, stream>>>(
            xlb, xrb, slots, deg, slotbase,
            We + (size_t)l * EDIM * HID, att + (size_t)l * NHEAD * CH, tmpp, redl, N);
        k_ln_gelu<<<((N * HID / 8) + 255) / 256, 256, 0, stream>>>(
            (const uint4*)tmpp, lnw + (size_t)l * HID, lnb + (size_t)l * HID, redl, M,
            (uint4*)hb, N * HID / 8);
    }
    k_gemm_mfma<false><<<dim3(gb, 1), 256, 0, stream>>>(
        hb, wz + (size_t)6 * 16384, wz + (size_t)6 * 16384, out, out, bout, N);
}

// Round 15
// 383.389 us; speedup vs baseline: 1.1760x; 1.0072x over previous
//
#include <hip/hip_runtime.h>
#include <hip/hip_bf16.h>
#include <math.h>

#define HID 128
#define NHEAD 4
#define CH 32
#define NLAYER 3
#define EDIM 3
#define EPSLN 1e-5f
#define SLOPE 0.2f
#define RSLOTS 1024   // LN-reduction slots (pairs) per layer
#define PAD_W -1e30f  // additive sentinel: exp2(part + PAD_W) == 0
#define LOG2E 1.4426950408889634f

typedef __bf16 bf16x8 __attribute__((ext_vector_type(8)));
typedef float f32x4 __attribute__((ext_vector_type(4)));
typedef float f32x2 __attribute__((ext_vector_type(2)));

__device__ __forceinline__ float bflo(unsigned d) { return __uint_as_float(d << 16); }
__device__ __forceinline__ float bfhi(unsigned d) { return __uint_as_float(d & 0xffff0000u); }

// sum via row-DPP adds (no LDS pipe)
#define DPP_ADD(x, ctrl) \
    (x + __int_as_float(__builtin_amdgcn_update_dpp(0, __float_as_int(x), ctrl, 0xf, 0xf, true)))

// ---------------------------------------------------------------- degree count + edge position
// pos[i] = this edge's arrival index at its destination (reuses the atomic's return value).
__global__ void k_count(const int* __restrict__ dst, int* __restrict__ deg,
                        int* __restrict__ pos, int E) {
    int i = blockIdx.x * blockDim.x + threadIdx.x;
    if (i < E) pos[i] = atomicAdd(&deg[dst[i]], 1);
}

// ---------------------------------------------------------------- hierarchical scan, phase A
// Each block scans 1024 group totals (group value = sum_{j<4} pad4(deg[4g+j])) ONCE:
// writes block-LOCAL exclusive prefix to outs[] and the block total to partial[b].
__global__ __launch_bounds__(1024) void k_scanA(const int* __restrict__ deg,
                                                int* __restrict__ outs,
                                                int* __restrict__ partial,
                                                int N, int G) {
    __shared__ int sw[16];
    int tid = threadIdx.x, lane = tid & 63, wid = tid >> 6;
    int i = blockIdx.x * 1024 + tid;
    int v = 0;
    if (i < G) {
        int n0 = 4 * i;
        if (n0 + 3 < N) {
            int4 d4 = *(const int4*)&deg[n0];
            v = ((d4.x + 3) & ~3) + ((d4.y + 3) & ~3) +
                ((d4.z + 3) & ~3) + ((d4.w + 3) & ~3);
        } else {
#pragma unroll
            for (int j = 0; j < 4; j++) {
                int n = n0 + j;
                if (n < N) v += (deg[n] + 3) & ~3;
            }
        }
    }
    int x = v;
#pragma unroll
    for (int o = 1; o < 64; o <<= 1) { int y = __shfl_up(x, o, 64); if (lane >= o) x += y; }
    if (lane == 63) sw[wid] = x;
    __syncthreads();
    if (tid < 16) {
        int s = sw[tid];
#pragma unroll
        for (int o = 1; o < 16; o <<= 1) { int y = __shfl_up(s, o, 64); if (tid >= o) s += y; }
        sw[tid] = s;
    }
    __syncthreads();
    int wofs = (wid == 0) ? 0 : sw[wid - 1];
    int incl = wofs + x;
    if (i < G) outs[i] = incl - v;
    if (tid == 0) partial[blockIdx.x] = sw[15];
}

// ---------------------------------------------------------------- per-node base + pad init
// slotbase[i] = outs[g] + prefix(partial, g>>10) + earlier nodes' pad4(deg) in group.
// Initializes ONLY the pad slots (deg..pad4-1): {src=-1, e=0}.
__global__ void k_nodepad(const int* __restrict__ deg, const int* __restrict__ outs,
                          const int* __restrict__ partial,
                          int* __restrict__ slotbase, int4* __restrict__ slots, int N) {
    int i = blockIdx.x * blockDim.x + threadIdx.x;
    if (i >= N) return;
    int g = i >> 2;
    int boff = 0;
    int nb = g >> 10;
    for (int b = 0; b < nb; b++) boff += partial[b];   // <=12 L2-hot, wave-uniform
    int base = outs[g] + boff;
    int i0 = g * 4;
#pragma unroll
    for (int j = 0; j < 3; j++)
        if (i0 + j < i) base += (deg[i0 + j] + 3) & ~3;
    slotbase[i] = base;
    int d = deg[i];
    int pd = (d + 3) & ~3;
    for (int j = d; j < pd; j++) slots[base + j] = make_int4(-1, 0, 0, 0);
}

// atomic-free: one 16B scattered store per edge: {src, e0, e1, e2}
__global__ void k_fill2(const int* __restrict__ src, const int* __restrict__ dst,
                        const float* __restrict__ eattr, const int* __restrict__ pos,
                        const int* __restrict__ slotbase, int4* __restrict__ slots, int E) {
    int i = blockIdx.x * blockDim.x + threadIdx.x;
    if (i < E) {
        int n = dst[i];
        int slot = slotbase[n] + pos[i];
        slots[slot] = make_int4(src[i], __float_as_int(eattr[3 * i]),
                                __float_as_int(eattr[3 * i + 1]),
                                __float_as_int(eattr[3 * i + 2]));
    }
}

// ---------------------------------------------------------------- fused weight prep + x cast
// blocks 0..6: bf16 + MFMA B-fragment swizzle of the 7 weight mats;
// blocks 7.. : fp32 x -> bf16 hb (the old k_cast).
__global__ __launch_bounds__(256) void k_prep(const float* __restrict__ Wl,
                                              const float* __restrict__ Wr,
                                              const float* __restrict__ Wout,
                                              __hip_bfloat16* __restrict__ wz,
                                              const float* __restrict__ xin,
                                              __hip_bfloat16* __restrict__ hb, int n) {
    int b = blockIdx.x;
    if (b < 7) {
        const float* src = (b < 6) ? ((b & 1) ? Wr + (size_t)(b >> 1) * 16384
                                              : Wl + (size_t)(b >> 1) * 16384)
                                   : Wout;
        for (int t = threadIdx.x; t < 16384; t += 256) {
            int j = t & 7, q = (t >> 3) & 63, nn = (t >> 9) & 7, s = t >> 12;
            int k = s * 32 + (q >> 4) * 8 + j;
            int c = nn * 16 + (q & 15);
            wz[(size_t)b * 16384 + t] = __float2bfloat16(src[k * 128 + c]);
        }
    } else {
        int i = ((b - 7) * 256 + threadIdx.x) * 4;
        if (i < n) {
            float4 v = *(const float4*)&xin[i];
            __hip_bfloat16 o[4] = {__float2bfloat16(v.x), __float2bfloat16(v.y),
                                   __float2bfloat16(v.z), __float2bfloat16(v.w)};
            *(ushort4*)&hb[i] = *(ushort4*)o;
        }
    }
}

// ---------------------------------------------------------------- MFMA GEMM
// Y = Xb(bf16) @ W(bf16 pre-swizzled); out bf16 (layers) or fp32+bias (final).
// PAIR: the two blocks reading A-strip x get bids congruent mod 8 -> same XCD L2
// (bid = (x/8)*16 + y*8 + x%8); tail-group holes return early (block-uniform).
template <bool BF16OUT, bool PAIR>
__global__ __launch_bounds__(256) void k_gemm_mfma(const __hip_bfloat16* __restrict__ Xb,
                                                   const __hip_bfloat16* __restrict__ Wz0,
                                                   const __hip_bfloat16* __restrict__ Wz1,
                                                   void* __restrict__ Y0v,
                                                   void* __restrict__ Y1v,
                                                   const float* __restrict__ bias,
                                                   int N, int NB) {
    __shared__ __hip_bfloat16 sW[16384];  // 32 KB
    int bx, by;
    if (PAIR) {
        int g = blockIdx.x >> 4;
        int r = blockIdx.x & 15;
        by = r >> 3;
        bx = g * 8 + (r & 7);
        if (bx >= NB) return;   // block-uniform: safe before barriers
    } else {
        bx = blockIdx.x;
        by = 0;
    }
    const __hip_bfloat16* Wz = by ? Wz1 : Wz0;
    void* Yv = by ? Y1v : Y0v;
    int tid = threadIdx.x;
    {
        const float4* s4 = (const float4*)Wz;
        float4* d4 = (float4*)sW;
#pragma unroll
        for (int i = 0; i < 8; i++) d4[tid + 256 * i] = s4[tid + 256 * i];
    }
    __syncthreads();

    int wv = tid >> 6, lane = tid & 63;
    int quad = lane >> 4, l16 = lane & 15;
    int mbase = bx * 128 + wv * 32;

    f32x4 acc[2][8];
#pragma unroll
    for (int mt = 0; mt < 2; mt++)
#pragma unroll
        for (int n = 0; n < 8; n++) acc[mt][n] = (f32x4){0.f, 0.f, 0.f, 0.f};

#pragma unroll
    for (int s = 0; s < 4; s++) {
        bf16x8 a[2];
#pragma unroll
        for (int mt = 0; mt < 2; mt++) {
            int row = mbase + mt * 16 + l16;
            row = (row < N) ? row : (N - 1);
            a[mt] = *(const bf16x8*)&Xb[(size_t)row * HID + s * 32 + quad * 8];
        }
#pragma unroll
        for (int n = 0; n < 8; n++) {
            bf16x8 b = *(const bf16x8*)&sW[((s * 8 + n) * 64 + lane) * 8];
            acc[0][n] = __builtin_amdgcn_mfma_f32_16x16x32_bf16(a[0], b, acc[0][n], 0, 0, 0);
            acc[1][n] = __builtin_amdgcn_mfma_f32_16x16x32_bf16(a[1], b, acc[1][n], 0, 0, 0);
        }
    }

    float bv[8];
#pragma unroll
    for (int n = 0; n < 8; n++) bv[n] = bias ? bias[n * 16 + l16] : 0.f;

#pragma unroll
    for (int mt = 0; mt < 2; mt++)
#pragma unroll
        for (int reg = 0; reg < 4; reg++) {
            int row = mbase + mt * 16 + quad * 4 + reg;
            if (row < N) {
                if (BF16OUT) {
                    __hip_bfloat16* yp = (__hip_bfloat16*)Yv + (size_t)row * HID + l16;
#pragma unroll
                    for (int n = 0; n < 8; n++) yp[n * 16] = __float2bfloat16(acc[mt][n][reg]);
                } else {
                    float* yp = (float*)Yv + (size_t)row * HID + l16;
#pragma unroll
                    for (int n = 0; n < 8; n++) yp[n * 16] = acc[mt][n][reg] + bv[n];
                }
            }
        }
}

// ---------------------------------------------------------------- GATv2 aggregate (per-node)
// One wave per node (R5 structure): lane owns 2 channels of EVERY edge; 4 edges/step.
// Slot record: int4 {src(-1=pad), e0, e1, e2}; records wave-uniform (scalar loads).
// PAIR-UNROLLED: 8 records + 8 independent 4B gathers issued per iteration, then
// 8 edge-computes; wave-uniform tail step.
__global__ __launch_bounds__(256) void k_aggregate(const __hip_bfloat16* __restrict__ xlb,
                                                   const __hip_bfloat16* __restrict__ xrb,
                                                   const int4* __restrict__ slots,
                                                   const int* __restrict__ deg,
                                                   const int* __restrict__ slotbase,
                                                   const float* __restrict__ We,
                                                   const float* __restrict__ att,
                                                   unsigned* __restrict__ tmpp,
                                                   float* __restrict__ red, int N) {
    int wid = threadIdx.x >> 6;
    int lane = threadIdx.x & 63;
    int node = blockIdx.x * 4 + wid;
    if (node >= N) return;
    int c0 = lane * 2;
    int head = lane >> 4;

    f32x2 we0, we1, we2;
    { float2 t = *(const float2*)&We[c0];            we0 = (f32x2){t.x, t.y}; }
    { float2 t = *(const float2*)&We[HID + c0];      we1 = (f32x2){t.x, t.y}; }
    { float2 t = *(const float2*)&We[2 * HID + c0];  we2 = (f32x2){t.x, t.y}; }
    float at0 = att[head * CH + (c0 & 31)] * LOG2E;        // fold log2e: exp2(m.at') == exp(m.at)
    float at1 = att[head * CH + (c0 & 31) + 1] * LOG2E;

    int base = __builtin_amdgcn_readfirstlane(slotbase[node]);
    int steps = __builtin_amdgcn_readfirstlane((deg[node] + 3) >> 2);

    unsigned dxr = *(const unsigned*)&xrb[(size_t)node * HID + c0];
    f32x2 xr2 = (f32x2){bflo(dxr), bfhi(dxr)};

    float l = 0.f;
    f32x2 Av = (f32x2){0.f, 0.f};

    const int4* vp = slots + base;

// 4B gather of this edge's 2 channels (pad -> row 0, in-bounds)
#define GATH2(v, d) { int si = max((v).x, 0); \
    d = *(const unsigned*)&xlb[(size_t)si * HID + c0]; }

// per-edge compute
#define EDGE(v, d) {                                                          \
    float e0 = __int_as_float((v).y);                                         \
    float e1 = __int_as_float((v).z);                                         \
    float e2 = __int_as_float((v).w);                                         \
    float padw = ((v).x < 0) ? PAD_W : 0.f;                                   \
    f32x2 xv = (f32x2){bflo(d), bfhi(d)};                                     \
    f32x2 m = __builtin_elementwise_fma(we2, (f32x2)e2, xv + xr2);            \
    m = __builtin_elementwise_fma(we1, (f32x2)e1, m);                         \
    m = __builtin_elementwise_fma(we0, (f32x2)e0, m);                         \
    m = __builtin_elementwise_max(m, m * SLOPE);                              \
    float part = fmaf(m.x, at0, m.y * at1);                                   \
    part = DPP_ADD(part, 0xB1);   /* quad_perm [1,0,3,2] */                   \
    part = DPP_ADD(part, 0x4E);   /* quad_perm [2,3,0,1] */                   \
    part = DPP_ADD(part, 0x141);  /* row_half_mirror (^7) */                  \
    part = DPP_ADD(part, 0x140);  /* row_mirror (^15) */                      \
    float p = __builtin_amdgcn_exp2f(part + padw);                            \
    l += p;                                                                   \
    Av = __builtin_elementwise_fma((f32x2)p, xv, Av);                         \
}

    int t = 0;
    for (; t + 2 <= steps; t += 2) {
        // 8 wave-uniform record loads (scalar pipe) ...
        int4 v0 = vp[4 * t + 0], v1 = vp[4 * t + 1], v2 = vp[4 * t + 2], v3 = vp[4 * t + 3];
        int4 v4 = vp[4 * t + 4], v5 = vp[4 * t + 5], v6 = vp[4 * t + 6], v7 = vp[4 * t + 7];
        // ... then 8 independent gathers in flight
        unsigned d0, d1, d2, d3, d4, d5, d6, d7;
        GATH2(v0, d0); GATH2(v1, d1); GATH2(v2, d2); GATH2(v3, d3);
        GATH2(v4, d4); GATH2(v5, d5); GATH2(v6, d6); GATH2(v7, d7);
        EDGE(v0, d0); EDGE(v1, d1); EDGE(v2, d2); EDGE(v3, d3);
        EDGE(v4, d4); EDGE(v5, d5); EDGE(v6, d6); EDGE(v7, d7);
    }
    if (t < steps) {  // wave-uniform tail (steps odd)
        int4 v0 = vp[4 * t + 0], v1 = vp[4 * t + 1], v2 = vp[4 * t + 2], v3 = vp[4 * t + 3];
        unsigned d0, d1, d2, d3;
        GATH2(v0, d0); GATH2(v1, d1); GATH2(v2, d2); GATH2(v3, d3);
        EDGE(v0, d0); EDGE(v1, d1); EDGE(v2, d2); EDGE(v3, d3);
    }
#undef GATH2
#undef EDGE

    float inv = 1.f / (l + 1e-16f);
    f32x2 o2 = Av * inv;
    __hip_bfloat16 pk[2] = {__float2bfloat16(o2.x), __float2bfloat16(o2.y)};
    tmpp[(size_t)node * (HID / 2) + lane] = *(unsigned*)pk;

    float ssum = o2.x + o2.y;             // LN stats from pre-rounded fp32
    float ssq = fmaf(o2.x, o2.x, o2.y * o2.y);
#pragma unroll
    for (int o = 32; o >= 1; o >>= 1) { ssum += __shfl_xor(ssum, o); ssq += __shfl_xor(ssq, o); }
    if (lane == 0) {
        int slot = (node & (RSLOTS - 1)) * 2;
        atomicAdd(&red[slot], ssum);
        atomicAdd(&red[slot + 1], ssq);
    }
}

// ---------------------------------------------------------------- LN + gelu (bf16 in/out)
// Each block redundantly reduces the layer's red[] (8 KB, L2-hot) -> no separate finish kernel.
__global__ __launch_bounds__(256) void k_ln_gelu(const uint4* __restrict__ in4,
                                                 const float* __restrict__ w,
                                                 const float* __restrict__ b,
                                                 const float* __restrict__ red,
                                                 float M,
                                                 uint4* __restrict__ out4, int n8) {
    __shared__ float ls[8];
    int tid = threadIdx.x;
    float s = 0.f, q = 0.f;
    const float2* r2 = (const float2*)red;
    for (int i = tid; i < RSLOTS; i += 256) { float2 rv = r2[i]; s += rv.x; q += rv.y; }
#pragma unroll
    for (int o = 32; o >= 1; o >>= 1) { s += __shfl_xor(s, o); q += __shfl_xor(q, o); }
    if ((tid & 63) == 0) { ls[(tid >> 6) * 2] = s; ls[(tid >> 6) * 2 + 1] = q; }
    __syncthreads();
    float S = ls[0] + ls[2] + ls[4] + ls[6];
    float Q = ls[1] + ls[3] + ls[5] + ls[7];
    float mean = S / M;
    float inv = rsqrtf(Q / M - mean * mean + EPSLN);

    int i = blockIdx.x * blockDim.x + tid;
    if (i >= n8) return;
    uint4 v = in4[i];
    int col = (i * 8) & 127;
    float4 w0 = *(const float4*)&w[col], w1 = *(const float4*)&w[col + 4];
    float4 b0 = *(const float4*)&b[col], b1 = *(const float4*)&b[col + 4];
    float r[8] = {bflo(v.x), bfhi(v.x), bflo(v.y), bfhi(v.y),
                  bflo(v.z), bfhi(v.z), bflo(v.w), bfhi(v.w)};
    float wr[8] = {w0.x, w0.y, w0.z, w0.w, w1.x, w1.y, w1.z, w1.w};
    float br[8] = {b0.x, b0.y, b0.z, b0.w, b1.x, b1.y, b1.z, b1.w};
    __hip_bfloat16 o[8];
#pragma unroll
    for (int j = 0; j < 8; j++) {
        float t = fmaf((r[j] - mean) * inv, wr[j], br[j]);
        o[j] = __float2bfloat16(0.5f * t * (1.f + erff(t * 0.70710678118654752f)));
    }
    out4[i] = *(uint4*)o;
}

// ---------------------------------------------------------------- launch
extern "C" void kernel_launch(void* const* d_in, const int* in_sizes, int n_in,
                              void* d_out, int out_size, void* d_ws, size_t ws_size,
                              hipStream_t stream) {
    const float* x = (const float*)d_in[0];
    const int* ei = (const int*)d_in[1];
    const float* eattr = (const float*)d_in[2];
    const float* Wl = (const float*)d_in[3];
    const float* Wr = (const float*)d_in[4];
    const float* We = (const float*)d_in[5];
    const float* att = (const float*)d_in[6];
    const float* lnw = (const float*)d_in[7];
    const float* lnb = (const float*)d_in[8];
    const float* Wout = (const float*)d_in[9];
    const float* bout = (const float*)d_in[10];
    float* out = (float*)d_out;

    int N = in_sizes[0] / HID;
    int E = in_sizes[1] / 2;
    int G = (N + 3) / 4;
    int SCAP = E + 8 * N;
    const int* src = ei;
    const int* dst = ei + E;

    char* w = (char*)d_ws;
    __hip_bfloat16* hb = (__hip_bfloat16*)w;   w += (size_t)N * HID * 2;
    __hip_bfloat16* xlb = (__hip_bfloat16*)w;  w += (size_t)N * HID * 2;
    __hip_bfloat16* xrb = (__hip_bfloat16*)w;  w += (size_t)N * HID * 2;
    unsigned* tmpp = (unsigned*)w;             w += (size_t)N * HID * 2;
    __hip_bfloat16* wz = (__hip_bfloat16*)w;   w += (size_t)7 * 16384 * 2;
    int4* slots = (int4*)w;       w += (size_t)SCAP * 16;
    int* pos = (int*)w;           w += (size_t)E * 4;
    // zero-region: deg, red (3 layers) contiguous -> ONE memset
    int* deg = (int*)w;           w += (size_t)N * 4;
    float* red = (float*)w;       w += (size_t)NLAYER * RSLOTS * 2 * 4;
    int* slotbase = (int*)w;      w += (size_t)N * 4;
    int* groupstart = (int*)w;    w += (size_t)(G + 1) * 4;
    int* partial = (int*)w;       w += 32 * 4;

    // ---- build + prep
    hipMemsetAsync(deg, 0, (size_t)(N + NLAYER * RSLOTS * 2) * 4, stream);
    k_count<<<(E + 255) / 256, 256, 0, stream>>>(dst, deg, pos, E);
    k_scanA<<<(G + 1023) / 1024, 1024, 0, stream>>>(deg, groupstart, partial, N, G);
    k_nodepad<<<(N + 255) / 256, 256, 0, stream>>>(deg, groupstart, partial, slotbase, slots, N);
    k_fill2<<<(E + 255) / 256, 256, 0, stream>>>(src, dst, eattr, pos, slotbase, slots, E);
    k_prep<<<7 + (N * HID / 4 + 255) / 256, 256, 0, stream>>>(Wl, Wr, Wout, wz, x, hb, N * HID);

    int gb = (N + 127) / 128;
    int gpair = 16 * ((gb + 7) / 8);
    float M = (float)N * (float)HID;
    for (int l = 0; l < NLAYER; l++) {
        float* redl = red + (size_t)l * RSLOTS * 2;
        k_gemm_mfma<true, true><<<gpair, 256, 0, stream>>>(
            hb, wz + (size_t)(2 * l) * 16384, wz + (size_t)(2 * l + 1) * 16384,
            xlb, xrb, nullptr, N, gb);
        k_aggregate<<<(N + 3) / 4, 256, 0, stream>>>(
            xlb, xrb, slots, deg, slotbase,
            We + (size_t)l * EDIM * HID, att + (size_t)l * NHEAD * CH, tmpp, redl, N);
        k_ln_gelu<<<((N * HID / 8) + 255) / 256, 256, 0, stream>>>(
            (const uint4*)tmpp, lnw + (size_t)l * HID, lnb + (size_t)l * HID, redl, M,
            (uint4*)hb, N * HID / 8);
    }
    k_gemm_mfma<false, false><<<gb, 256, 0, stream>>>(
        hb, wz + (size_t)6 * 16384, wz + (size_t)6 * 16384, out, out, bout, N, gb);
}